// Round 6
// baseline (164.892 us; speedup 1.0000x reference)
//
#include <hip/hip_runtime.h>
#include <hip/hip_bf16.h>
#include <stdint.h>

typedef __attribute__((ext_vector_type(4))) float          f32x4;
typedef __attribute__((ext_vector_type(8))) short          short8;
typedef __attribute__((ext_vector_type(4))) unsigned short u16x4;

#define F            20480
#define NROWS        4096
#define NPAD         144
#define BK           128
#define CHUNK_BYTES  (NPAD * BK * 2)   /* 36864 bytes per staged B K-chunk */
#define TOTAL_CHUNKS (F / BK)          /* 160 */
#define MB           256               /* GEMM rows per block (8 waves x 32) */

static __device__ __forceinline__ unsigned short f2bf(float f) {
    unsigned u = __builtin_bit_cast(unsigned, f);
    unsigned r = (u + 0x7FFFu + ((u >> 16) & 1u)) >> 16;   // round-to-nearest-even
    return (unsigned short)r;
}

// ---------------------------------------------------------------------------
// Prep: weights f32 -> bf16, per K-chunk (128 k) in *inverse-swizzled* order
// so linear global_load_lds staging yields an LDS image where
//   lds_byte(n, k) = n*256 + ((k*2) ^ ((n&7)<<4))
// (<=2-way bank aliasing on the fragment ds_read_b128 pattern = free; R1/R4/R5
// measured 0 SQ_LDS_BANK_CONFLICT with this XOR algebra).
// Rows: n<128 -> w_acc[n], n==128/129 -> w_psqt[0/1], n>=130 -> 0 (pad).
// ---------------------------------------------------------------------------
__global__ __launch_bounds__(256) void prep_b(const float* __restrict__ w_acc,
                                              const float* __restrict__ w_psqt,
                                              unsigned short* __restrict__ Bp) {
    int gid = blockIdx.x * 256 + threadIdx.x;      // 737280 threads, 8 B each
    int p8    = gid * 8;                           // output byte offset
    int chunk = p8 / CHUNK_BYTES;
    int win   = p8 % CHUNK_BYTES;
    int n     = win >> 8;                          // row within chunk (0..143)
    int sb    = win & 255;                         // byte within row (8-aligned)
    int kbyte = sb ^ ((n & 7) << 4);               // inverse swizzle (8-align kept)
    int k0    = chunk * BK + (kbyte >> 1);         // multiple of 4 -> f32x4 OK
    f32x4 v = {0.f, 0.f, 0.f, 0.f};
    if (n < 128)      v = *(const f32x4*)(w_acc  + (size_t)n * F + k0);
    else if (n < 130) v = *(const f32x4*)(w_psqt + (size_t)(n - 128) * F + k0);
    u16x4 pk;
    pk[0] = f2bf(v[0]); pk[1] = f2bf(v[1]); pk[2] = f2bf(v[2]); pk[3] = f2bf(v[3]);
    *(u16x4*)((char*)Bp + p8) = pk;
}

// ---------------------------------------------------------------------------
// Main GEMM: grid (32 row-groups, KS=8 k-slices) = 256 blocks = 1/CU.
// 512 threads = 8 waves; wave w owns rows [w*32, w*32+32) of the block's 256.
// Counted-vmcnt pipeline (T3/T4): triple-buffered B in LDS; per iter t:
//   s_waitcnt vmcnt(4)  -> stage(t)+A(t) complete, stage(t+1) stays in flight
//   s_barrier           -> all waves' stage(t) LDS writes visible
//   cvt A(t); issue A(t+1); issue stage(t+2) -> buf (t+2)%3 (never the buf
//     being read; its readers all passed the top-of-t barrier) ; MFMA
// The memory pipe never drains -> no per-iter round-trip bubble.
// Tail iters re-issue clamped (in-bounds, unused) loads to keep vmcnt uniform.
// vmcnt(4): waves 0-3 stage 5 lines, waves 4-7 stage 4; 4 is exact for the
// latter and 1-over-strict (a full-iter-old load) for the former.
// ---------------------------------------------------------------------------
__global__ __launch_bounds__(512, 2) void gemm_main(
    const float* __restrict__ white, const float* __restrict__ black,
    const unsigned short* __restrict__ Bp, _Float16* __restrict__ partial,
    int chunks_per_ks)
{
    __shared__ alignas(16) unsigned short Blds[3][CHUNK_BYTES / 2];

    const int tid  = threadIdx.x;
    const int wave = tid >> 6;       // 0..7
    const int lane = tid & 63;
    const int g    = lane >> 4;      // k-group 0..3
    const int r16  = lane & 15;      // row/col within 16-tile

    const int rg   = blockIdx.x;     // 0..31
    const int row0 = rg * MB;        // GEMM row (0..8191), whole block same side
    const float* Aside = (row0 < NROWS) ? white : black;
    const int arow0 = row0 & (NROWS - 1);

    const int chunk0 = blockIdx.y * chunks_per_ks;
    const int nch    = chunks_per_ks;
    const int clast  = chunk0 + nch - 1;

    // A fragment row pointers (m=0,1), g*8 k-offset folded in
    const float* aRow0 = Aside + (size_t)(arow0 + wave * 32 + r16) * F + g * 8;
    const float* aRow1 = aRow0 + (size_t)16 * F;

    f32x4 apf[2][4][2];   // [m][kk][lo/hi] prefetched A f32 (single buffer)
    f32x4 acc[2][9];
    const f32x4 zero = {0.f, 0.f, 0.f, 0.f};
    #pragma unroll
    for (int m = 0; m < 2; ++m)
        #pragma unroll
        for (int n = 0; n < 9; ++n) acc[m][n] = zero;

    auto stageB = [&](int buf, int chunk) {
        const char* src = (const char*)Bp + (size_t)chunk * CHUNK_BYTES + lane * 16;
        char* dst = (char*)(&Blds[buf][0]);
        #pragma unroll
        for (int line = 0; line < 5; ++line) {
            int li = wave + line * 8;            // 8 waves split 36 lines
            if (li < 36)
                __builtin_amdgcn_global_load_lds(
                    (const __attribute__((address_space(1))) void*)(src + li * 1024),
                    (__attribute__((address_space(3))) void*)(dst + li * 1024),
                    16, 0, 0);
        }
    };

    auto loadA = [&](int kbase) {
        #pragma unroll
        for (int m = 0; m < 2; ++m) {
            const float* p = (m ? aRow1 : aRow0) + kbase;
            #pragma unroll
            for (int kk = 0; kk < 4; ++kk) {
                apf[m][kk][0] = *(const f32x4*)(p + kk * 32);
                apf[m][kk][1] = *(const f32x4*)(p + kk * 32 + 4);
            }
        }
    };

    // Prologue: stage(0), A(0), stage(1)  (issue order matters for vmcnt math)
    stageB(0, chunk0);
    loadA(chunk0 * BK);
    stageB(1, chunk0 + 1 <= clast ? chunk0 + 1 : clast);

    for (int t = 0; t < nch; ++t) {
        asm volatile("s_waitcnt vmcnt(4)" ::: "memory");
        __builtin_amdgcn_sched_barrier(0);
        __builtin_amdgcn_s_barrier();

        // convert this iter's A to bf16 fragments (k = kk*32 + g*8 + j)
        short8 afr[2][4];
        #pragma unroll
        for (int m = 0; m < 2; ++m)
            #pragma unroll
            for (int kk = 0; kk < 4; ++kk) {
                short8 r;
                #pragma unroll
                for (int j = 0; j < 4; ++j) {
                    r[j]     = (short)f2bf(apf[m][kk][0][j]);
                    r[j + 4] = (short)f2bf(apf[m][kk][1][j]);
                }
                afr[m][kk] = r;
            }

        // Issue next A (overwrites apf; cvt above already consumed it —
        // in-order issue makes the WAR safe), then stage(t+2). Clamped
        // re-issues at the tail keep per-wave vmcnt counts uniform.
        {
            int cA = chunk0 + t + 1; if (cA > clast) cA = clast;
            loadA(cA * BK);
            int cS = chunk0 + t + 2; if (cS > clast) cS = clast;
            stageB((t + 2) % 3, cS);
        }

        const char* bb = (const char*)(&Blds[t % 3][0]);
        #pragma unroll
        for (int kk = 0; kk < 4; ++kk) {
            #pragma unroll
            for (int n = 0; n < 9; ++n) {
                const int nn  = n * 16 + r16;
                const int off = nn * 256 + ((kk * 64 + g * 16) ^ ((nn & 7) << 4));
                short8 bf = *(const short8*)(bb + off);   // ds_read_b128, swizzled
                acc[0][n] = __builtin_amdgcn_mfma_f32_16x16x32_bf16(afr[0][kk], bf, acc[0][n], 0, 0, 0);
                acc[1][n] = __builtin_amdgcn_mfma_f32_16x16x32_bf16(afr[1][kk], bf, acc[1][n], 0, 0, 0);
            }
        }
    }

    // C-write (f16): C/D layout col = lane&15, row = (lane>>4)*4 + j
    _Float16* prow = partial + ((size_t)blockIdx.y * 8192 + row0 + wave * 32 + g * 4) * NPAD;
    #pragma unroll
    for (int m = 0; m < 2; ++m)
        #pragma unroll
        for (int n = 0; n < 9; ++n)
            #pragma unroll
            for (int j = 0; j < 4; ++j)
                prow[(m * 16 + j) * NPAD + n * 16 + r16] = (_Float16)acc[m][n][j];
}

// ---------------------------------------------------------------------------
// Epilogue: reduce split-K f16 partials, bias+clip, 128->2 layer, psqt.
// One wave per batch row; lane covers acc indices {lane, lane+64}.
// ---------------------------------------------------------------------------
__global__ __launch_bounds__(256) void epilogue(
    const _Float16* __restrict__ partial, const float* __restrict__ b_acc,
    const float* __restrict__ w_layer, float* __restrict__ out, int KS)
{
    const int wave = threadIdx.x >> 6, lane = threadIdx.x & 63;
    const int b = blockIdx.x * 4 + wave;     // 0..4095
    float sw0 = 0, sw1 = 0, sb0 = 0, sb1 = 0, q0 = 0, q1 = 0;
    for (int ks = 0; ks < KS; ++ks) {
        const _Float16* Pw = partial + ((size_t)ks * 8192 + b) * NPAD;
        const _Float16* Pb = partial + ((size_t)ks * 8192 + NROWS + b) * NPAD;
        sw0 += (float)Pw[lane];      sw1 += (float)Pw[lane + 64];
        sb0 += (float)Pb[lane];      sb1 += (float)Pb[lane + 64];
        q0  += (float)Pw[128] - (float)Pb[128];
        q1  += (float)Pw[129] - (float)Pb[129];
    }
    float wa0 = fminf(fmaxf(sw0 + b_acc[lane], 0.f), 1.f);
    float wa1 = fminf(fmaxf(sw1 + b_acc[lane + 64], 0.f), 1.f);
    float ba0 = fminf(fmaxf(sb0 + b_acc[lane], 0.f), 1.f);
    float ba1 = fminf(fmaxf(sb1 + b_acc[lane + 64], 0.f), 1.f);
    float d0 = wa0 - ba0, d1 = wa1 - ba1;
    float p0 = w_layer[lane] * d0       + w_layer[lane + 64] * d1;
    float p1 = w_layer[128 + lane] * d0 + w_layer[192 + lane] * d1;
    #pragma unroll
    for (int off = 32; off >= 1; off >>= 1) {
        p0 += __shfl_xor(p0, off, 64);
        p1 += __shfl_xor(p1, off, 64);
    }
    if (lane == 0) {
        out[b * 2 + 0] = q0 + p0;
        out[b * 2 + 1] = q1 + p1;
    }
}

// ---------------------------------------------------------------------------
extern "C" void kernel_launch(void* const* d_in, const int* in_sizes, int n_in,
                              void* d_out, int out_size, void* d_ws, size_t ws_size,
                              hipStream_t stream)
{
    const float* white   = (const float*)d_in[0];
    const float* black   = (const float*)d_in[1];
    const float* w_psqt  = (const float*)d_in[2];
    const float* w_acc   = (const float*)d_in[3];
    const float* b_acc   = (const float*)d_in[4];
    const float* w_layer = (const float*)d_in[5];
    float* out = (float*)d_out;

    const size_t bbytes = (size_t)TOTAL_CHUNKS * CHUNK_BYTES;  // 5,898,240
    unsigned short* Bp = (unsigned short*)d_ws;
    _Float16* partial = (_Float16*)((char*)d_ws + bbytes);

    const size_t per_ks = (size_t)8192 * NPAD * 2;             // 2.36 MB (f16)
    int KS = 1;
    const int cands[5] = {8, 5, 4, 2, 1};
    for (int i = 0; i < 5; ++i)
        if (bbytes + (size_t)cands[i] * per_ks <= ws_size) { KS = cands[i]; break; }
    int chunks_per_ks = TOTAL_CHUNKS / KS;

    prep_b   <<<dim3(2880),   dim3(256), 0, stream>>>(w_acc, w_psqt, Bp);
    gemm_main<<<dim3(32, KS), dim3(512), 0, stream>>>(white, black, Bp, partial, chunks_per_ks);
    epilogue <<<dim3(1024),   dim3(256), 0, stream>>>(partial, b_acc, w_layer, out, KS);
}

// Round 7
// 147.403 us; speedup vs baseline: 1.1186x; 1.1186x over previous
//
#include <hip/hip_runtime.h>
#include <hip/hip_bf16.h>
#include <stdint.h>

typedef __attribute__((ext_vector_type(4))) float          f32x4;
typedef __attribute__((ext_vector_type(8))) short          short8;
typedef __attribute__((ext_vector_type(4))) unsigned short u16x4;

#define F            20480
#define NROWS        4096
#define NPAD         144
#define BK           256
#define CHUNK_BYTES  (NPAD * BK * 2)   /* 73728 bytes per staged B K-chunk */
#define TOTAL_CHUNKS (F / BK)          /* 80 */
#define MB           256               /* GEMM rows per block (8 waves x 32) */

static __device__ __forceinline__ unsigned short f2bf(float f) {
    unsigned u = __builtin_bit_cast(unsigned, f);
    unsigned r = (u + 0x7FFFu + ((u >> 16) & 1u)) >> 16;   // round-to-nearest-even
    return (unsigned short)r;
}

// ---------------------------------------------------------------------------
// Prep: weights f32 -> bf16, per K-chunk (256 k) in *inverse-swizzled* order
// so linear global_load_lds staging yields an LDS image where
//   lds_byte(n, k) = n*512 + ((k*2) ^ ((n&7)<<4))
// (same bank-slot algebra that measured 0 SQ_LDS_BANK_CONFLICT in R1/R4).
// Rows: n<128 -> w_acc[n], n==128/129 -> w_psqt[0/1], n>=130 -> 0 (pad).
// ---------------------------------------------------------------------------
__global__ __launch_bounds__(256) void prep_b(const float* __restrict__ w_acc,
                                              const float* __restrict__ w_psqt,
                                              unsigned short* __restrict__ Bp) {
    int gid = blockIdx.x * 256 + threadIdx.x;      // 737280 threads, 8 B each
    int p8    = gid * 8;                           // output byte offset
    int chunk = p8 / CHUNK_BYTES;
    int win   = p8 % CHUNK_BYTES;
    int n     = win >> 9;                          // row within chunk (0..143)
    int sb    = win & 511;                         // byte within row (8-aligned)
    int kbyte = sb ^ ((n & 7) << 4);               // inverse swizzle (8-align kept)
    int k0    = chunk * BK + (kbyte >> 1);         // multiple of 4 -> f32x4 OK
    f32x4 v = {0.f, 0.f, 0.f, 0.f};
    if (n < 128)      v = *(const f32x4*)(w_acc  + (size_t)n * F + k0);
    else if (n < 130) v = *(const f32x4*)(w_psqt + (size_t)(n - 128) * F + k0);
    u16x4 pk;
    pk[0] = f2bf(v[0]); pk[1] = f2bf(v[1]); pk[2] = f2bf(v[2]); pk[3] = f2bf(v[3]);
    *(u16x4*)((char*)Bp + p8) = pk;
}

// ---------------------------------------------------------------------------
// Main GEMM: grid (32 row-groups, KS=8 k-slices) = 256 blocks = 1/CU.
// 512 threads = 8 waves; wave w owns rows [w*32, w*32+32) of the block's 256.
// R5 structure (plain __syncthreads double-buffer — the compiler schedules the
// interior; m141: don't pin) scaled to BK=256:
//   - 10 barrier/vmcnt(0) drains per slice (was 20) -> half the bubble count
//   - A read granule 1 KB/row/iter (was 512 B) -> better DRAM efficiency
// A handled in two half-iter phases so apf stays at 64 VGPRs; the mid-iter
// cvt of half1 gets a compiler-inserted *counted* vmcnt (stage loads remain
// outstanding). LDS 147.5 KB double-buffered; ~225 unified regs -> 2
// waves/SIMD, no spill.
// ---------------------------------------------------------------------------
__global__ __launch_bounds__(512, 2) void gemm_main(
    const float* __restrict__ white, const float* __restrict__ black,
    const unsigned short* __restrict__ Bp, _Float16* __restrict__ partial,
    int chunks_per_ks)
{
    __shared__ alignas(16) unsigned short Blds[2][CHUNK_BYTES / 2];

    const int tid  = threadIdx.x;
    const int wave = tid >> 6;       // 0..7
    const int lane = tid & 63;
    const int g    = lane >> 4;      // k-group 0..3
    const int r16  = lane & 15;      // row/col within 16-tile

    const int rg   = blockIdx.x;     // 0..31
    const int row0 = rg * MB;        // GEMM row (0..8191), whole block same side
    const float* Aside = (row0 < NROWS) ? white : black;
    const int arow0 = row0 & (NROWS - 1);

    const int chunk0 = blockIdx.y * chunks_per_ks;
    const int nch    = chunks_per_ks;

    // A fragment row pointers (m=0,1), g*8 k-offset folded in
    const float* aRow0 = Aside + (size_t)(arow0 + wave * 32 + r16) * F + g * 8;
    const float* aRow1 = aRow0 + (size_t)16 * F;

    f32x4 apf[2][4][2];   // [m][kk][lo/hi] prefetched A f32 — one 128-k half
    f32x4 acc[2][9];
    const f32x4 zero = {0.f, 0.f, 0.f, 0.f};
    #pragma unroll
    for (int m = 0; m < 2; ++m)
        #pragma unroll
        for (int n = 0; n < 9; ++n) acc[m][n] = zero;

    auto stageB = [&](int buf, int chunk) {
        const char* src = (const char*)Bp + (size_t)chunk * CHUNK_BYTES + lane * 16;
        char* dst = (char*)(&Blds[buf][0]);
        #pragma unroll
        for (int line = 0; line < 9; ++line) {     // 72 lines / 8 waves = 9 each
            int li = wave + line * 8;
            __builtin_amdgcn_global_load_lds(
                (const __attribute__((address_space(1))) void*)(src + li * 1024),
                (__attribute__((address_space(3))) void*)(dst + li * 1024),
                16, 0, 0);
        }
    };

    // load one 128-k half of A: half h covers k = kbase + h*128 + [0,128)
    auto loadA = [&](int kbase, int h) {
        #pragma unroll
        for (int m = 0; m < 2; ++m) {
            const float* p = (m ? aRow1 : aRow0) + kbase + h * 128;
            #pragma unroll
            for (int kk = 0; kk < 4; ++kk) {
                apf[m][kk][0] = *(const f32x4*)(p + kk * 32);
                apf[m][kk][1] = *(const f32x4*)(p + kk * 32 + 4);
            }
        }
    };

    // convert apf -> bf16 fragments (k = kk*32 + g*8 + j within the half)
    short8 afr0[2][4], afr1[2][4];
    auto cvtA = [&](short8 (&afr)[2][4]) {
        #pragma unroll
        for (int m = 0; m < 2; ++m)
            #pragma unroll
            for (int kk = 0; kk < 4; ++kk) {
                short8 r;
                #pragma unroll
                for (int j = 0; j < 4; ++j) {
                    r[j]     = (short)f2bf(apf[m][kk][0][j]);
                    r[j + 4] = (short)f2bf(apf[m][kk][1][j]);
                }
                afr[m][kk] = r;
            }
    };

    // Prologue
    stageB(0, chunk0);
    loadA(chunk0 * BK, 0);

    for (int t = 0; t < nch; ++t) {
        __syncthreads();   // drains vmcnt -> B(t) + A(t,h0) ready (issued ~half to full iter ago)

        cvtA(afr0);                        // consume A(t,h0)
        loadA((chunk0 + t) * BK, 1);       // issue A(t,h1) (WAR-safe after cvt)
        if (t + 1 < nch)
            stageB((t + 1) & 1, chunk0 + t + 1);   // prev readers passed top barrier

        const char* bb = (const char*)(&Blds[t & 1][0]);
        #pragma unroll
        for (int kk = 0; kk < 4; ++kk) {
            #pragma unroll
            for (int n = 0; n < 9; ++n) {
                const int nn  = n * 16 + r16;
                const int off = nn * 512 + ((kk * 64 + g * 16) ^ ((nn & 7) << 4));
                short8 bf = *(const short8*)(bb + off);   // ds_read_b128, swizzled
                acc[0][n] = __builtin_amdgcn_mfma_f32_16x16x32_bf16(afr0[0][kk], bf, acc[0][n], 0, 0, 0);
                acc[1][n] = __builtin_amdgcn_mfma_f32_16x16x32_bf16(afr0[1][kk], bf, acc[1][n], 0, 0, 0);
            }
        }

        cvtA(afr1);                        // compiler inserts counted vmcnt for A(t,h1)
        if (t + 1 < nch)
            loadA((chunk0 + t + 1) * BK, 0);   // issue A(t+1,h0)

        #pragma unroll
        for (int kk = 0; kk < 4; ++kk) {
            #pragma unroll
            for (int n = 0; n < 9; ++n) {
                const int nn  = n * 16 + r16;
                const int off = nn * 512 + (((kk + 4) * 64 + g * 16) ^ ((nn & 7) << 4));
                short8 bf = *(const short8*)(bb + off);
                acc[0][n] = __builtin_amdgcn_mfma_f32_16x16x32_bf16(afr1[0][kk], bf, acc[0][n], 0, 0, 0);
                acc[1][n] = __builtin_amdgcn_mfma_f32_16x16x32_bf16(afr1[1][kk], bf, acc[1][n], 0, 0, 0);
            }
        }
    }

    // C-write (f16): C/D layout col = lane&15, row = (lane>>4)*4 + j
    _Float16* prow = partial + ((size_t)blockIdx.y * 8192 + row0 + wave * 32 + g * 4) * NPAD;
    #pragma unroll
    for (int m = 0; m < 2; ++m)
        #pragma unroll
        for (int n = 0; n < 9; ++n)
            #pragma unroll
            for (int j = 0; j < 4; ++j)
                prow[(m * 16 + j) * NPAD + n * 16 + r16] = (_Float16)acc[m][n][j];
}

// ---------------------------------------------------------------------------
// Epilogue: reduce split-K f16 partials, bias+clip, 128->2 layer, psqt.
// One wave per batch row; lane covers acc indices {lane, lane+64}.
// ---------------------------------------------------------------------------
__global__ __launch_bounds__(256) void epilogue(
    const _Float16* __restrict__ partial, const float* __restrict__ b_acc,
    const float* __restrict__ w_layer, float* __restrict__ out, int KS)
{
    const int wave = threadIdx.x >> 6, lane = threadIdx.x & 63;
    const int b = blockIdx.x * 4 + wave;     // 0..4095
    float sw0 = 0, sw1 = 0, sb0 = 0, sb1 = 0, q0 = 0, q1 = 0;
    for (int ks = 0; ks < KS; ++ks) {
        const _Float16* Pw = partial + ((size_t)ks * 8192 + b) * NPAD;
        const _Float16* Pb = partial + ((size_t)ks * 8192 + NROWS + b) * NPAD;
        sw0 += (float)Pw[lane];      sw1 += (float)Pw[lane + 64];
        sb0 += (float)Pb[lane];      sb1 += (float)Pb[lane + 64];
        q0  += (float)Pw[128] - (float)Pb[128];
        q1  += (float)Pw[129] - (float)Pb[129];
    }
    float wa0 = fminf(fmaxf(sw0 + b_acc[lane], 0.f), 1.f);
    float wa1 = fminf(fmaxf(sw1 + b_acc[lane + 64], 0.f), 1.f);
    float ba0 = fminf(fmaxf(sb0 + b_acc[lane], 0.f), 1.f);
    float ba1 = fminf(fmaxf(sb1 + b_acc[lane + 64], 0.f), 1.f);
    float d0 = wa0 - ba0, d1 = wa1 - ba1;
    float p0 = w_layer[lane] * d0       + w_layer[lane + 64] * d1;
    float p1 = w_layer[128 + lane] * d0 + w_layer[192 + lane] * d1;
    #pragma unroll
    for (int off = 32; off >= 1; off >>= 1) {
        p0 += __shfl_xor(p0, off, 64);
        p1 += __shfl_xor(p1, off, 64);
    }
    if (lane == 0) {
        out[b * 2 + 0] = q0 + p0;
        out[b * 2 + 1] = q1 + p1;
    }
}

// ---------------------------------------------------------------------------
extern "C" void kernel_launch(void* const* d_in, const int* in_sizes, int n_in,
                              void* d_out, int out_size, void* d_ws, size_t ws_size,
                              hipStream_t stream)
{
    const float* white   = (const float*)d_in[0];
    const float* black   = (const float*)d_in[1];
    const float* w_psqt  = (const float*)d_in[2];
    const float* w_acc   = (const float*)d_in[3];
    const float* b_acc   = (const float*)d_in[4];
    const float* w_layer = (const float*)d_in[5];
    float* out = (float*)d_out;

    const size_t bbytes = (size_t)TOTAL_CHUNKS * CHUNK_BYTES;  // 5,898,240
    unsigned short* Bp = (unsigned short*)d_ws;
    _Float16* partial = (_Float16*)((char*)d_ws + bbytes);

    const size_t per_ks = (size_t)8192 * NPAD * 2;             // 2.36 MB (f16)
    int KS = 1;
    const int cands[5] = {8, 5, 4, 2, 1};
    for (int i = 0; i < 5; ++i)
        if (bbytes + (size_t)cands[i] * per_ks <= ws_size) { KS = cands[i]; break; }
    int chunks_per_ks = TOTAL_CHUNKS / KS;

    prep_b   <<<dim3(2880),   dim3(256), 0, stream>>>(w_acc, w_psqt, Bp);
    gemm_main<<<dim3(32, KS), dim3(512), 0, stream>>>(white, black, Bp, partial, chunks_per_ks);
    epilogue <<<dim3(1024),   dim3(256), 0, stream>>>(partial, b_acc, w_layer, out, KS);
}